// Round 8
// baseline (1107.237 us; speedup 1.0000x reference)
//
#include <hip/hip_runtime.h>
#include <hip/hip_bf16.h>
#include <math.h>

// Problem constants
#define B_  2
#define T_  2048
#define C_  1536
#define H_  12
#define KV_ 4
#define D_  128
#define M_  (B_*T_)   // 4096 rows
#define REP_ (H_/KV_) // 3
#define NQKV_ 2560    // fused q|k|v output width
#define KK_  1536     // K for both big GEMMs
#define NKT_ 24       // KK_/64 K-tiles
#define NBLK_ 512     // persistent grid: 2 blocks/CU x 256 CUs (LDS-bound)

typedef __bf16 bf16x8 __attribute__((ext_vector_type(8)));
typedef float  f32x4  __attribute__((ext_vector_type(4)));
typedef unsigned u32x4 __attribute__((ext_vector_type(4)));

union BCast { u32x4 u; bf16x8 b; };

__device__ inline bf16x8 ldb8(const ushort* p) {
    BCast c; c.u = *reinterpret_cast<const u32x4*>(p); return c.b;
}

__device__ inline ushort f2bf(float f) {
    union { float f; unsigned u; } v; v.f = f;
    unsigned u = v.u;
    return (ushort)((u + 0x7FFF + ((u >> 16) & 1)) >> 16);
}

__device__ inline float bf2f(ushort u) {
    union { unsigned u; float f; } v; v.u = (unsigned)u << 16;
    return v.f;
}

// async global->LDS, 16 bytes per lane; lds base must be wave-uniform
__device__ inline void async_copy16(const ushort* g, ushort* l) {
    __builtin_amdgcn_global_load_lds(
        (const __attribute__((address_space(1))) unsigned*)g,
        (__attribute__((address_space(3))) unsigned*)l, 16, 0, 0);
}

// d-permutation for rope-pair locality: swap middle two 32-blocks of each head.
__device__ __host__ inline int dperm(int d) {
    return (d < 32) ? d : (d < 64 ? d + 32 : (d < 96 ? d - 32 : d));
}

#define MFMA16(va, vb, d) d = __builtin_amdgcn_mfma_f32_16x16x32_bf16(va, vb, d, 0, 0, 0)

// ---------------------------------------------------------------------------
// Grid-wide sense-reversing barrier. Co-residency of all NBLK_ blocks is
// structurally guaranteed (64KB LDS -> exactly 2 blocks/CU; launch_bounds
// (256,2)). Device-scope atomics resolve at the die-coherent LLC;
// __threadfence release/acquire emits the per-XCD L2 writeback/invalidate
// required across non-coherent L2s (Guideline 16). bar self-resets.
// ---------------------------------------------------------------------------
__device__ inline void gsync(unsigned* bar, unsigned nb) {
    __syncthreads();                      // drains vmcnt/lgkm for all waves
    if (threadIdx.x == 0) {
        __threadfence();                  // release: wbL2 this XCD
        unsigned gen = __hip_atomic_load(bar + 1, __ATOMIC_RELAXED,
                                         __HIP_MEMORY_SCOPE_AGENT);
        unsigned prev = __hip_atomic_fetch_add(bar, 1u, __ATOMIC_ACQ_REL,
                                               __HIP_MEMORY_SCOPE_AGENT);
        if (prev == nb - 1u) {
            __hip_atomic_store(bar, 0u, __ATOMIC_RELAXED,
                               __HIP_MEMORY_SCOPE_AGENT);
            __hip_atomic_fetch_add(bar + 1, 1u, __ATOMIC_RELEASE,
                                   __HIP_MEMORY_SCOPE_AGENT);
        } else {
            while (__hip_atomic_load(bar + 1, __ATOMIC_ACQUIRE,
                                     __HIP_MEMORY_SCOPE_AGENT) == gen)
                __builtin_amdgcn_s_sleep(2);
        }
        __threadfence();                  // acquire: inv L1/L2 this CU/XCD
    }
    __syncthreads();
}

// ---------------------------------------------------------------------------
// Stage: fused segmented fp32->bf16 cast (one float4 per thread per iter)
// ---------------------------------------------------------------------------
#define SEG0 1572864   // x      : 4096*1536/4
#define SEG1 2162688   // + Wq   : 1536*1536/4
#define SEG2 2359296   // + Wk   : 512*1536/4
#define SEG3 2555904   // + Wv   : 512*1536/4
#define SEG4 3145728   // + Wproj: 1536*1536/4
#define ROW4 384       // float4s per 1536-col row
__device__ __forceinline__ void cast_body(int it,
        const float* __restrict__ x,  const float* __restrict__ Wq,
        const float* __restrict__ Wk, const float* __restrict__ Wv,
        const float* __restrict__ Wp, ushort* __restrict__ xb,
        ushort* __restrict__ Wqkvb,   ushort* __restrict__ Wpb) {
    const int i = it * 256 + threadIdx.x;
    float4 v; size_t dst4; ushort* dstp;
    if (i < SEG0) {
        v = ((const float4*)x)[i]; dstp = xb; dst4 = i;
    } else if (i < SEG1) {
        const int j = i - SEG0;
        const int r = j / ROW4, c4 = j - r * ROW4;
        const int d = r & 127, hh = r >> 7;
        v = ((const float4*)Wq)[j]; dstp = Wqkvb;
        dst4 = (size_t)(hh * 128 + dperm(d)) * ROW4 + c4;
    } else if (i < SEG2) {
        const int j = i - SEG1;
        const int r = j / ROW4, c4 = j - r * ROW4;
        const int d = r & 127, g = r >> 7;
        v = ((const float4*)Wk)[j]; dstp = Wqkvb;
        dst4 = (size_t)(1536 + g * 128 + dperm(d)) * ROW4 + c4;
    } else if (i < SEG3) {
        const int j = i - SEG2;
        v = ((const float4*)Wv)[j]; dstp = Wqkvb;
        dst4 = (size_t)2048 * ROW4 + j;
    } else {
        const int j = i - SEG3;
        v = ((const float4*)Wp)[j]; dstp = Wpb; dst4 = j;
    }
    ((ushort4*)dstp)[dst4] = make_ushort4(f2bf(v.x), f2bf(v.y), f2bf(v.z), f2bf(v.w));
}

// ---------------------------------------------------------------------------
// Stage: 128x128 GEMM tile (r7 body verbatim; LDS carved from smem).
// smem: ldsA = smem[0..16383], ldsB = smem[16384..32767] (2 bufs each).
// ---------------------------------------------------------------------------
template<int EPI>
__device__ __forceinline__ void gemm_tile(int orig, int nwg, ushort* smem,
        const ushort* __restrict__ A,  const ushort* __restrict__ Bm,
        ushort* __restrict__ Qp, ushort* __restrict__ Kp,
        ushort* __restrict__ vbuf, float* __restrict__ Cf,
        const float* __restrict__ cosb, const float* __restrict__ sinb) {
    ushort* ldsA = smem;            // 2 x 8192
    ushort* ldsB = smem + 16384;    // 2 x 8192
    const int tid  = threadIdx.x;
    const int wave = tid >> 6, lane = tid & 63;
    const int m16 = lane & 15, quad = lane >> 4;
    const int WM = wave >> 1, WN = wave & 1;

    // XCD-aware bijective remap, M-fastest within each XCD chunk.
    const int vid = (orig & 7) * (nwg >> 3) + (orig >> 3);
    const int bxT = vid >> 5;              // gy = 32
    const int byT = vid & 31;
    const int bm = byT << 7, bn = bxT << 7;

    const int r = tid >> 3;                              // 0..31
    const int slot8 = ((tid & 7) ^ (r & 7)) << 3;        // swizzled col (elems)
    const ushort* Ag = A  + (size_t)(bm + r) * KK_ + slot8;
    const ushort* Bg = Bm + (size_t)(bn + r) * KK_ + slot8;
    const size_t row32 = (size_t)32 * KK_;

    auto stage = [&](const ushort* Gp, ushort* ldsOp, int kc) {
        ushort* base = ldsOp + wave * 512;   // wave-uniform, lanes add 16B
        const ushort* g = Gp + kc;
        async_copy16(g,             base);
        async_copy16(g +   row32,   base + 2048);
        async_copy16(g + 2*row32,   base + 4096);
        async_copy16(g + 3*row32,   base + 6144);
    };

    const int swzu = (m16 & 7) << 3;
    const int k0u  = (quad * 8) ^ swzu;
    const int k1u  = (32 + quad * 8) ^ swzu;
    const ushort* aB0 = ldsA + ((WM * 64 + m16) << 6) + k0u;
    const ushort* aB1 = ldsA + ((WM * 64 + m16) << 6) + k1u;
    const ushort* bB0 = ldsB + ((WN * 64 + m16) << 6) + k0u;
    const ushort* bB1 = ldsB + ((WN * 64 + m16) << 6) + k1u;

    f32x4 acc[4][4];
    #pragma unroll
    for (int i = 0; i < 4; i++)
        #pragma unroll
        for (int j = 0; j < 4; j++) acc[i][j] = (f32x4){0.f, 0.f, 0.f, 0.f};

    stage(Bg, ldsB, 0);        stage(Ag, ldsA, 0);
    stage(Bg, ldsB + 8192, 64); stage(Ag, ldsA + 8192, 64);
    __builtin_amdgcn_s_waitcnt(0x0F78);   // vmcnt(8): tile0 landed
    __builtin_amdgcn_sched_barrier(0);
    __builtin_amdgcn_s_barrier();
    __builtin_amdgcn_sched_barrier(0);

    #pragma unroll 1
    for (int kt = 0; kt < NKT_; kt++) {
        const int bo = (kt & 1) ? 8192 : 0;
        bf16x8 a[8], b[8];
        #pragma unroll
        for (int mf = 0; mf < 4; mf++) {
            a[mf*2+0] = ldb8(aB0 + bo + mf*1024);
            a[mf*2+1] = ldb8(aB1 + bo + mf*1024);
        }
        #pragma unroll
        for (int nf = 0; nf < 4; nf++) {
            b[nf*2+0] = ldb8(bB0 + bo + nf*1024);
            b[nf*2+1] = ldb8(bB1 + bo + nf*1024);
        }
        __builtin_amdgcn_s_setprio(1);
        #pragma unroll
        for (int mf = 0; mf < 4; mf++)
            #pragma unroll
            for (int nf = 0; nf < 4; nf++) {
                MFMA16(a[mf*2+0], b[nf*2+0], acc[mf][nf]);
                MFMA16(a[mf*2+1], b[nf*2+1], acc[mf][nf]);
            }
        __builtin_amdgcn_s_setprio(0);
        if (kt < NKT_ - 1) {
            __builtin_amdgcn_sched_barrier(0);
            __builtin_amdgcn_s_barrier();      // Bar1: cur buf read-complete
            __builtin_amdgcn_sched_barrier(0);
            if (kt < NKT_ - 2) {
                stage(Bg, ldsB + ((kt & 1) ? 8192 : 0), (kt + 2) << 6);
                stage(Ag, ldsA + ((kt & 1) ? 8192 : 0), (kt + 2) << 6);
                __builtin_amdgcn_s_waitcnt(0x0F78);  // vmcnt(8): kt+1 landed
            } else {
                __builtin_amdgcn_s_waitcnt(0x0F70);  // vmcnt(0): drain tail
            }
            __builtin_amdgcn_sched_barrier(0);
            __builtin_amdgcn_s_barrier();      // Bar2: nxt buf certified
            __builtin_amdgcn_sched_barrier(0);
        }
    }
    __syncthreads();   // quiesce before epilogue LDS reuse

    if constexpr (EPI == 0) {
        if (bn >= 2048) {
            const int cb = bn - 2048 + WN * 64;
            #pragma unroll
            for (int mf = 0; mf < 4; mf++) {
                const int rl = WM*64 + mf*16 + quad*4;
                #pragma unroll
                for (int reg = 0; reg < 4; reg++) {
                    ushort* vr = vbuf + (size_t)(bm + rl + reg) * 512 + cb + m16;
                    #pragma unroll
                    for (int nf = 0; nf < 4; nf++)
                        vr[nf*16] = f2bf(acc[mf][nf][reg]);
                }
            }
        } else {
            float* ssqS = (float*)ldsA;   // [128][2] floats, 1 KB
            #pragma unroll
            for (int mf = 0; mf < 4; mf++) {
                #pragma unroll
                for (int reg = 0; reg < 4; reg++) {
                    float v = acc[mf][0][reg]*acc[mf][0][reg] + acc[mf][1][reg]*acc[mf][1][reg]
                            + acc[mf][2][reg]*acc[mf][2][reg] + acc[mf][3][reg]*acc[mf][3][reg];
                    v += __shfl_xor(v, 1); v += __shfl_xor(v, 2);
                    v += __shfl_xor(v, 4); v += __shfl_xor(v, 8);
                    if (m16 == 0) {
                        const int rl = WM*64 + mf*16 + quad*4 + reg;
                        ssqS[rl*2 + WN] = v;
                    }
                }
            }
            __syncthreads();

            const bool isq = (bn < 1536);
            const float osc = isq ? (1.2f * 1.2f * 0.08838834764831845f) : 1.0f;
            const int hh  = isq ? (bn >> 7) : ((bn - 1536) >> 7);
            const int nh  = isq ? H_ : KV_;
            ushort* outp  = isq ? Qp : Kp;

            #pragma unroll
            for (int mf = 0; mf < 4; mf++) {
                #pragma unroll
                for (int reg = 0; reg < 4; reg++) {
                    const int rl = WM*64 + mf*16 + quad*4 + reg;
                    const int row = bm + rl;
                    const float tot = ssqS[rl*2] + ssqS[rl*2 + 1];
                    const float sc = rsqrtf(tot * (1.0f/128.0f) + 1.1920928955078125e-07f) * osc;
                    const int b = row >> 11, t = row & (T_ - 1);
                    ushort* orow = outp + ((size_t)(b * nh + hh) * T_ + t) * D_;
                    #pragma unroll
                    for (int nf = 0; nf < 2; nf++) {
                        const int ipair = WN * 32 + nf*16 + m16;
                        const float c = cosb[t*64 + ipair], s = sinb[t*64 + ipair];
                        const float x1 = acc[mf][nf][reg], x2 = acc[mf][nf+2][reg];
                        const int oc = WN * 64 + nf*16 + m16;
                        orow[oc]      = f2bf((x1*c + x2*s) * sc);
                        orow[oc + 32] = f2bf((x2*c - x1*s) * sc);
                    }
                }
            }
        }
    } else {
        #pragma unroll
        for (int mf = 0; mf < 4; mf++) {
            const int rl = WM*64 + mf*16 + quad*4;
            #pragma unroll
            for (int reg = 0; reg < 4; reg++) {
                float* cr = Cf + (size_t)(bm + rl + reg) * C_ + bn + WN*64 + m16;
                #pragma unroll
                for (int nf = 0; nf < 4; nf++)
                    cr[nf*16] = acc[mf][nf][reg];
            }
        }
    }
    __syncthreads();   // protect LDS before next grid-stride tile reuses it
}

// ---------------------------------------------------------------------------
// Stage: ve-gate + transpose (smem: gateS floats @0, tile [128][66] @+128)
// ---------------------------------------------------------------------------
__device__ __forceinline__ void gate_body(int tIdx, ushort* smem,
        const ushort* __restrict__ vbuf, const float* __restrict__ x,
        const float* __restrict__ ve, const float* __restrict__ Wg,
        ushort* __restrict__ Vt) {
    const int t0 = (tIdx & 31) << 6;
    const int g  = (tIdx >> 5) & 3;
    const int b  = tIdx >> 7;
    float*  gateS = (float*)smem;        // 64 floats
    ushort* tile  = smem + 128;          // [128][66]
    const int tid = threadIdx.x;
    if (tid < 64) {
        const float* xr = x + (size_t)(b * T_ + t0 + tid) * C_;
        float acc = 0.f;
        #pragma unroll
        for (int c = 0; c < 12; c++) acc += xr[c] * Wg[g * 12 + c];
        gateS[tid] = 3.0f / (1.0f + __expf(-acc));
    }
    __syncthreads();
    #pragma unroll
    for (int i = 0; i < 32; i++) {
        int idx = i * 256 + tid;       // 0..8191
        int r = idx >> 7;              // t within tile
        int d = idx & 127;
        size_t offv = (size_t)(b * T_ + t0 + r) * 512 + g * D_ + d;
        tile[d * 66 + r] = f2bf(bf2f(vbuf[offv]) + gateS[r] * ve[offv]);
    }
    __syncthreads();
    ushort* ob = Vt + ((size_t)(b * KV_ + g) * D_) * T_ + t0;
    #pragma unroll
    for (int i = 0; i < 32; i++) {
        int idx = i * 256 + tid;
        int d = idx >> 6;              // 0..127
        int c = idx & 63;
        ob[(size_t)d * T_ + c] = tile[d * 66 + c];
    }
    __syncthreads();   // protect LDS before next tile
}

// ---------------------------------------------------------------------------
// Stage: flash attention (r7 double-buffered body; smem: Ks@0 2x4096,
// Vs@8192 2x4096, Pl@16384 4x640)
// ---------------------------------------------------------------------------
__device__ __forceinline__ void attn_body(int tIdx, ushort* smem,
        const ushort* __restrict__ Qp, const ushort* __restrict__ Kp,
        const ushort* __restrict__ Vt, ushort* __restrict__ Y,
        const int* __restrict__ wptr) {
    const int t0 = (tIdx & 31) << 6;
    const int hb = tIdx >> 5;
    const int h  = hb % H_;
    const int b  = hb / H_;
    const int g  = h / REP_;
    const int tid  = threadIdx.x;
    const int wave = tid >> 6, lane = tid & 63;
    const int m16 = lane & 15, quad = lane >> 4;

    ushort* Ks = smem;             // [2][4096]
    ushort* Vs = smem + 8192;      // [2][4096]
    ushort* pw = smem + 16384 + wave * 640;

    const int w = *wptr;
    const bool windowed = (w >= 0 && w < T_);
    const unsigned wu = windowed ? (unsigned)w : 0x7FFFFFFFu;
    int s_lo = 0;
    if (windowed) { s_lo = t0 - w; if (s_lo < 0) s_lo = 0; }
    const int s_hi = t0 + 63;
    const int ss0 = s_lo & ~31;
    const int NST = ((s_hi - ss0) >> 5) + 1;   // >= 2 always
    const int tw = t0 + wave * 16;

    const ushort* qrow = Qp + ((size_t)(b * H_ + h) * T_ + tw + m16) * D_ + quad * 8;
    bf16x8 qa[4];
    #pragma unroll
    for (int kc = 0; kc < 4; kc++) qa[kc] = ldb8(qrow + kc * 32);

    const ushort* kbase = Kp + (size_t)(b * KV_ + g) * T_ * D_;
    const ushort* vbase = Vt + (size_t)(b * KV_ + g) * D_ * T_;

    const int c0 = wave, c1 = wave + 4;
    const ushort* kg0 = kbase + (size_t)((c0 & 1) * 16 + (lane >> 2)) * D_ + (c0 >> 1) * 32 + (lane & 3) * 8;
    const ushort* kg1 = kbase + (size_t)((c1 & 1) * 16 + (lane >> 2)) * D_ + (c1 >> 1) * 32 + (lane & 3) * 8;
    const ushort* vg0 = vbase + (size_t)(c0 * 16 + (lane >> 2)) * T_ + (lane & 3) * 8;
    const ushort* vg1 = vbase + (size_t)(c1 * 16 + (lane >> 2)) * T_ + (lane & 3) * 8;
    const int kl0o = c0 * 512, kl1o = c1 * 512;

    auto stg = [&](int st, int buf) {
        const int ss = ss0 + (st << 5);
        const size_t koff = (size_t)ss * D_;
        async_copy16(kg0 + koff, Ks + buf * 4096 + kl0o);
        async_copy16(kg1 + koff, Ks + buf * 4096 + kl1o);
        async_copy16(vg0 + ss,   Vs + buf * 4096 + kl0o);
        async_copy16(vg1 + ss,   Vs + buf * 4096 + kl1o);
    };

    f32x4 o[8];
    #pragma unroll
    for (int dt = 0; dt < 8; dt++) o[dt] = (f32x4){0.f, 0.f, 0.f, 0.f};
    f32x4 lacc = (f32x4){0.f, 0.f, 0.f, 0.f};
    BCast onesc; onesc.u = (u32x4){0x3F803F80u, 0x3F803F80u, 0x3F803F80u, 0x3F803F80u};
    const bf16x8 ones = onesc.b;

    stg(0, 0); stg(1, 1);
    __builtin_amdgcn_s_waitcnt(0x0F74);   // vmcnt(4)
    __builtin_amdgcn_sched_barrier(0);
    __builtin_amdgcn_s_barrier();
    __builtin_amdgcn_sched_barrier(0);

    #pragma unroll 1
    for (int st = 0; st < NST; st++) {
        const int ss = ss0 + (st << 5);
        const ushort* KsB = Ks + (st & 1) * 4096;
        const ushort* VsB = Vs + (st & 1) * 4096;

        f32x4 s0 = (f32x4){0.f,0.f,0.f,0.f};
        f32x4 s1 = (f32x4){0.f,0.f,0.f,0.f};
        #pragma unroll
        for (int kc = 0; kc < 4; kc++) {
            bf16x8 kf0 = ldb8(KsB + kc * 1024 + m16 * 32 + quad * 8);
            bf16x8 kf1 = ldb8(KsB + kc * 1024 + (16 + m16) * 32 + quad * 8);
            s0 = __builtin_amdgcn_mfma_f32_16x16x32_bf16(qa[kc], kf0, s0, 0, 0, 0);
            s1 = __builtin_amdgcn_mfma_f32_16x16x32_bf16(qa[kc], kf1, s1, 0, 0, 0);
        }

        const int sA = ss + m16, sB = ss + 16 + m16;
        #pragma unroll
        for (int reg = 0; reg < 4; reg++) {
            const int t = tw + quad * 4 + reg;
            const float pa = ((unsigned)(t - sA) <= wu) ? __expf(s0[reg]) : 0.f;
            const float pb = ((unsigned)(t - sB) <= wu) ? __expf(s1[reg]) : 0.f;
            pw[(quad * 4 + reg) * 40 + m16]      = f2bf(pa);
            pw[(quad * 4 + reg) * 40 + 16 + m16] = f2bf(pb);
        }

        __builtin_amdgcn_s_waitcnt(0xc07f);   // lgkmcnt(0), leave vmcnt alone
        bf16x8 pfrag = ldb8(pw + m16 * 40 + quad * 8);

        #pragma unroll
        for (int dt = 0; dt < 8; dt++) {
            bf16x8 vf = ldb8(VsB + (dt * 16 + m16) * 32 + quad * 8);
            o[dt] = __builtin_amdgcn_mfma_f32_16x16x32_bf16(pfrag, vf, o[dt], 0, 0, 0);
        }
        lacc = __builtin_amdgcn_mfma_f32_16x16x32_bf16(pfrag, ones, lacc, 0, 0, 0);

        if (st < NST - 1) {
            __builtin_amdgcn_sched_barrier(0);
            __builtin_amdgcn_s_barrier();      // Bar1: cur buf read-complete
            __builtin_amdgcn_sched_barrier(0);
            if (st < NST - 2) {
                stg(st + 2, st & 1);
                __builtin_amdgcn_s_waitcnt(0x0F74);  // vmcnt(4): st+1 landed
            } else {
                __builtin_amdgcn_s_waitcnt(0x0F70);  // vmcnt(0): drain tail
            }
            __builtin_amdgcn_sched_barrier(0);
            __builtin_amdgcn_s_barrier();      // Bar2: nxt buf certified
            __builtin_amdgcn_sched_barrier(0);
        }
    }

    float inv[4];
    #pragma unroll
    for (int reg = 0; reg < 4; reg++) inv[reg] = 1.0f / lacc[reg];
    ushort* yb = Y + ((size_t)(b * T_ + tw + quad * 4) * H_ + h) * D_ + m16;
    #pragma unroll
    for (int reg = 0; reg < 4; reg++)
        #pragma unroll
        for (int dt = 0; dt < 8; dt++)
            yb[(size_t)reg * H_ * D_ + dt * 16] = f2bf(o[dt][reg] * inv[reg]);
    __syncthreads();   // protect LDS before next tile
}

// ---------------------------------------------------------------------------
// Persistent mega-kernel: 5 stages, 4 grid barriers, zero kernel boundaries.
// ---------------------------------------------------------------------------
__global__ __launch_bounds__(256, 2) void mega(
        const float* __restrict__ x,  const float* __restrict__ ve,
        const float* __restrict__ cosb, const float* __restrict__ sinb,
        const float* __restrict__ Wq, const float* __restrict__ Wk,
        const float* __restrict__ Wv, const float* __restrict__ Wp,
        const float* __restrict__ Wg, const int* __restrict__ wptr,
        ushort* xb, ushort* vbuf, ushort* Qp, ushort* Kp, ushort* Vt,
        ushort* yb16, ushort* Wqkvb, ushort* Wpb, float* out,
        unsigned* bar) {
    __shared__ ushort smem[32768];   // 64 KB, re-carved per stage
    const unsigned nb = gridDim.x;
    const int bid = blockIdx.x;

    // S1: cast (12288 tiles)
    for (int t = bid; t < SEG4 / 256; t += nb)
        cast_body(t, x, Wq, Wk, Wv, Wp, xb, Wqkvb, Wpb);
    gsync(bar, nb);

    // S2: qkv GEMM (640 tiles)
    for (int t = bid; t < 640; t += nb)
        gemm_tile<0>(t, 640, smem, xb, Wqkvb, Qp, Kp, vbuf, nullptr, cosb, sinb);
    gsync(bar, nb);

    // S3: ve-gate + transpose (256 tiles)
    for (int t = bid; t < 256; t += nb)
        gate_body(t, smem, vbuf, x, ve, Wg, Vt);
    gsync(bar, nb);

    // S4: flash attention (768 tiles)
    for (int t = bid; t < 768; t += nb)
        attn_body(t, smem, Qp, Kp, Vt, yb16, wptr);
    gsync(bar, nb);

    // S5: proj GEMM (384 tiles)
    for (int t = bid; t < 384; t += nb)
        gemm_tile<1>(t, 384, smem, yb16, Wpb, nullptr, nullptr, nullptr, out,
                     nullptr, nullptr);
}

// ---------------------------------------------------------------------------
extern "C" void kernel_launch(void* const* d_in, const int* in_sizes, int n_in,
                              void* d_out, int out_size, void* d_ws, size_t ws_size,
                              hipStream_t stream) {
    const float* x     = (const float*)d_in[0];
    const float* ve    = (const float*)d_in[1];
    const float* cosb  = (const float*)d_in[2];
    const float* sinb  = (const float*)d_in[3];
    const float* Wq    = (const float*)d_in[4];
    const float* Wk    = (const float*)d_in[5];
    const float* Wv    = (const float*)d_in[6];
    const float* Wproj = (const float*)d_in[7];
    const float* Wg    = (const float*)d_in[8];
    const int*   wptr  = (const int*)d_in[9];
    float* out = (float*)d_out;

    // workspace layout (all bf16/ushort), ~60 MB + barrier tail
    ushort* xb    = (ushort*)d_ws;                    // M*C
    ushort* vbuf  = xb    + (size_t)M_ * C_;          // M*512
    ushort* Qp    = vbuf  + (size_t)M_ * 512;         // M*C (permuted d)
    ushort* Kp    = Qp    + (size_t)M_ * C_;          // M*512 (permuted d)
    ushort* Vt    = Kp    + (size_t)M_ * 512;         // M*512
    ushort* yb16  = Vt    + (size_t)M_ * 512;         // M*C
    ushort* Wqkvb = yb16  + (size_t)M_ * C_;          // 2560*C (q/k rows dperm'd)
    ushort* Wpb   = Wqkvb + (size_t)NQKV_ * C_;       // C*C
    unsigned* bar = (unsigned*)(Wpb + (size_t)C_ * C_);  // 2 words

    hipMemsetAsync(bar, 0, 64, stream);

    mega<<<NBLK_, 256, 0, stream>>>(x, ve, cosb, sinb, Wq, Wk, Wv, Wproj, Wg,
                                    wptr, xb, vbuf, Qp, Kp, Vt, yb16, Wqkvb,
                                    Wpb, out, bar);
}

// Round 9
// 238.497 us; speedup vs baseline: 4.6426x; 4.6426x over previous
//
#include <hip/hip_runtime.h>
#include <hip/hip_bf16.h>
#include <math.h>

// Problem constants
#define B_  2
#define T_  2048
#define C_  1536
#define H_  12
#define KV_ 4
#define D_  128
#define M_  (B_*T_)   // 4096 rows
#define REP_ (H_/KV_) // 3
#define NQKV_ 2560    // fused q|k|v output width
#define KK_  1536     // K for both big GEMMs
#define NKT_ 24       // KK_/64 K-tiles

typedef __bf16 bf16x8 __attribute__((ext_vector_type(8)));
typedef float  f32x4  __attribute__((ext_vector_type(4)));
typedef unsigned u32x4 __attribute__((ext_vector_type(4)));

union BCast { u32x4 u; bf16x8 b; };

__device__ inline bf16x8 ldb8(const ushort* p) {
    BCast c; c.u = *reinterpret_cast<const u32x4*>(p); return c.b;
}

__device__ inline ushort f2bf(float f) {
    union { float f; unsigned u; } v; v.f = f;
    unsigned u = v.u;
    return (ushort)((u + 0x7FFF + ((u >> 16) & 1)) >> 16);
}

__device__ inline float bf2f(ushort u) {
    union { unsigned u; float f; } v; v.u = (unsigned)u << 16;
    return v.f;
}

// async global->LDS, 16 bytes per lane; lds base must be wave-uniform
__device__ inline void async_copy16(const ushort* g, ushort* l) {
    __builtin_amdgcn_global_load_lds(
        (const __attribute__((address_space(1))) unsigned*)g,
        (__attribute__((address_space(3))) unsigned*)l, 16, 0, 0);
}

// d-permutation for rope-pair locality: swap middle two 32-blocks of each head.
__device__ __host__ inline int dperm(int d) {
    return (d < 32) ? d : (d < 64 ? d + 32 : (d < 96 ? d - 32 : d));
}

#define MFMA16(va, vb, d) d = __builtin_amdgcn_mfma_f32_16x16x32_bf16(va, vb, d, 0, 0, 0)

// ---------------------------------------------------------------------------
// 128x128 GEMM, 2 blocks/CU: C[M,N] = A[M,K]*B[N,K]^T.  (r7/r6 structure —
// the established HIP-source plateau for this shape: 7 schedule variants all
// land 424-474 TF; r8's persistent-fusion attempt was 4x WORSE. Kept as-is.)
// r9 CHANGE: EPI==0 v-tiles (bn>=2048) now fuse the ve-gate + transpose
// epilogue and write Vt DIRECTLY (gate_vt kernel + vbuf round-trip deleted).
// A v-tile covers exactly one KV group's 128 d-cols x 128 t-rows.
// ---------------------------------------------------------------------------
template<int EPI>
__global__ __launch_bounds__(256, 2) void gemm128(const ushort* __restrict__ A,
                                                  const ushort* __restrict__ Bm,
                                                  ushort* __restrict__ Qp,
                                                  ushort* __restrict__ Kp,
                                                  ushort* __restrict__ Vt,
                                                  float* __restrict__ Cf,
                                                  const float* __restrict__ cosb,
                                                  const float* __restrict__ sinb,
                                                  const float* __restrict__ xf,
                                                  const float* __restrict__ ve,
                                                  const float* __restrict__ Wg) {
    __shared__ ushort smem[32768];     // 64 KB: GEMM bufs; re-carved in epi
    ushort* ldsA = smem;               // 2 x 8192
    ushort* ldsB = smem + 16384;       // 2 x 8192
    const int tid  = threadIdx.x;
    const int wave = tid >> 6, lane = tid & 63;
    const int m16 = lane & 15, quad = lane >> 4;
    const int WM = wave >> 1, WN = wave & 1;

    // XCD-aware bijective remap, M-fastest within each XCD chunk (B-panel
    // L2 reuse). nwg % 8 == 0 for both grids (640, 384).
    const int nwg  = gridDim.x * gridDim.y;
    const int orig = blockIdx.y * gridDim.x + blockIdx.x;
    const int vid  = (orig & 7) * (nwg >> 3) + (orig >> 3);
    const int bxT  = vid >> 5;             // gy = 32
    const int byT  = vid & 31;
    const int bm = byT << 7, bn = bxT << 7;

    // staging: linear LDS dest, inverse-swizzled global source (rule 21).
    const int r = tid >> 3;                              // 0..31
    const int slot8 = ((tid & 7) ^ (r & 7)) << 3;        // swizzled col (elems)
    const ushort* Ag = A  + (size_t)(bm + r) * KK_ + slot8;
    const ushort* Bg = Bm + (size_t)(bn + r) * KK_ + slot8;
    const size_t row32 = (size_t)32 * KK_;

    auto stage = [&](const ushort* Gp, ushort* ldsOp, int kc) {
        ushort* base = ldsOp + wave * 512;   // wave-uniform, lanes add 16B
        const ushort* g = Gp + kc;
        async_copy16(g,             base);
        async_copy16(g +   row32,   base + 2048);
        async_copy16(g + 2*row32,   base + 4096);
        async_copy16(g + 3*row32,   base + 6144);
    };

    const int swzu = (m16 & 7) << 3;
    const int k0u  = (quad * 8) ^ swzu;
    const int k1u  = (32 + quad * 8) ^ swzu;
    const ushort* aB0 = ldsA + ((WM * 64 + m16) << 6) + k0u;
    const ushort* aB1 = ldsA + ((WM * 64 + m16) << 6) + k1u;
    const ushort* bB0 = ldsB + ((WN * 64 + m16) << 6) + k0u;
    const ushort* bB1 = ldsB + ((WN * 64 + m16) << 6) + k1u;

    f32x4 acc[4][4];
    #pragma unroll
    for (int i = 0; i < 4; i++)
        #pragma unroll
        for (int j = 0; j < 4; j++) acc[i][j] = (f32x4){0.f, 0.f, 0.f, 0.f};

    stage(Bg, ldsB, 0);         stage(Ag, ldsA, 0);
    stage(Bg, ldsB + 8192, 64); stage(Ag, ldsA + 8192, 64);
    __builtin_amdgcn_s_waitcnt(0x0F78);   // vmcnt(8): tile0 landed
    __builtin_amdgcn_sched_barrier(0);
    __builtin_amdgcn_s_barrier();
    __builtin_amdgcn_sched_barrier(0);

    #pragma unroll 1
    for (int kt = 0; kt < NKT_; kt++) {
        const int bo = (kt & 1) ? 8192 : 0;
        bf16x8 a[8], b[8];
        #pragma unroll
        for (int mf = 0; mf < 4; mf++) {
            a[mf*2+0] = ldb8(aB0 + bo + mf*1024);
            a[mf*2+1] = ldb8(aB1 + bo + mf*1024);
        }
        #pragma unroll
        for (int nf = 0; nf < 4; nf++) {
            b[nf*2+0] = ldb8(bB0 + bo + nf*1024);
            b[nf*2+1] = ldb8(bB1 + bo + nf*1024);
        }
        __builtin_amdgcn_s_setprio(1);
        #pragma unroll
        for (int mf = 0; mf < 4; mf++)
            #pragma unroll
            for (int nf = 0; nf < 4; nf++) {
                MFMA16(a[mf*2+0], b[nf*2+0], acc[mf][nf]);
                MFMA16(a[mf*2+1], b[nf*2+1], acc[mf][nf]);
            }
        __builtin_amdgcn_s_setprio(0);
        if (kt < NKT_ - 1) {
            __builtin_amdgcn_sched_barrier(0);
            __builtin_amdgcn_s_barrier();      // Bar1: cur buf read-complete
            __builtin_amdgcn_sched_barrier(0);
            if (kt < NKT_ - 2) {
                stage(Bg, ldsB + ((kt & 1) ? 8192 : 0), (kt + 2) << 6);
                stage(Ag, ldsA + ((kt & 1) ? 8192 : 0), (kt + 2) << 6);
                __builtin_amdgcn_s_waitcnt(0x0F78);  // vmcnt(8): kt+1 landed
            } else {
                __builtin_amdgcn_s_waitcnt(0x0F70);  // vmcnt(0): drain tail
            }
            __builtin_amdgcn_sched_barrier(0);
            __builtin_amdgcn_s_barrier();      // Bar2: nxt buf certified
            __builtin_amdgcn_sched_barrier(0);
        }
    }
    __syncthreads();   // quiesce before epilogue LDS reuse

    // ---------------- epilogues ----------------
    if constexpr (EPI == 0) {
        if (bn >= 2048) {
            // v tile: fused ve-gate + transpose, direct to Vt[b][g][d][t].
            const int g  = (bn - 2048) >> 7;
            const int bb = bm >> 11;           // batch
            const int tb = bm & (T_ - 1);      // tile t-base
            ushort* tile = smem;               // [128 d][130] = 33,280 B
            float* gateS = (float*)(smem + 128 * 130);   // 128 floats
            // (a) acc -> LDS[d][t_local]  (raw v)
            #pragma unroll
            for (int mf = 0; mf < 4; mf++)
                #pragma unroll
                for (int reg = 0; reg < 4; reg++) {
                    const int tl = WM*64 + mf*16 + quad*4 + reg;
                    #pragma unroll
                    for (int nf = 0; nf < 4; nf++) {
                        const int d = WN*64 + nf*16 + m16;
                        tile[d*130 + tl] = f2bf(acc[mf][nf][reg]);
                    }
                }
            // gate per row: 3*sigmoid(x[row,0:12] @ Wg[g])
            if (tid < 128) {
                const float* xr = xf + (size_t)(bb * T_ + tb + tid) * C_;
                float a = 0.f;
                #pragma unroll
                for (int c = 0; c < 12; c++) a += xr[c] * Wg[g * 12 + c];
                gateS[tid] = 3.0f / (1.0f + __expf(-a));
            }
            __syncthreads();
            // (b) t-major: tile[d][t] += gate[t]*ve[t][d]  (coalesced ve)
            const float* veb = ve + (size_t)(bb * T_ + tb) * 512 + g * D_;
            #pragma unroll
            for (int i = 0; i < 64; i++) {
                const int idx = i * 256 + tid;     // 0..16383
                const int tl = idx >> 7, d = idx & 127;
                const float vv = bf2f(tile[d*130 + tl])
                               + gateS[tl] * veb[(size_t)tl * 512 + d];
                tile[d*130 + tl] = f2bf(vv);
            }
            __syncthreads();
            // (c) d-major: LDS -> Vt, coalesced along t
            ushort* ob = Vt + ((size_t)(bb * KV_ + g) * D_) * T_ + tb;
            #pragma unroll
            for (int i = 0; i < 64; i++) {
                const int idx = i * 256 + tid;
                const int d = idx >> 7, c = idx & 127;
                ob[(size_t)d * T_ + c] = tile[d*130 + c];
            }
        } else {
            // q/k tile (one head per tile): RMS (rotation-invariant) + rope
            float* ssqS = (float*)ldsA;   // [128][2] floats, 1 KB
            #pragma unroll
            for (int mf = 0; mf < 4; mf++) {
                #pragma unroll
                for (int reg = 0; reg < 4; reg++) {
                    float v = acc[mf][0][reg]*acc[mf][0][reg] + acc[mf][1][reg]*acc[mf][1][reg]
                            + acc[mf][2][reg]*acc[mf][2][reg] + acc[mf][3][reg]*acc[mf][3][reg];
                    v += __shfl_xor(v, 1); v += __shfl_xor(v, 2);
                    v += __shfl_xor(v, 4); v += __shfl_xor(v, 8);
                    if (m16 == 0) {
                        const int rl = WM*64 + mf*16 + quad*4 + reg;
                        ssqS[rl*2 + WN] = v;
                    }
                }
            }
            __syncthreads();

            const bool isq = (bn < 1536);
            const float osc = isq ? (1.2f * 1.2f * 0.08838834764831845f) : 1.0f;
            const int hh  = isq ? (bn >> 7) : ((bn - 1536) >> 7);
            const int nh  = isq ? H_ : KV_;
            ushort* outp  = isq ? Qp : Kp;

            #pragma unroll
            for (int mf = 0; mf < 4; mf++) {
                #pragma unroll
                for (int reg = 0; reg < 4; reg++) {
                    const int rl = WM*64 + mf*16 + quad*4 + reg;
                    const int row = bm + rl;
                    const float tot = ssqS[rl*2] + ssqS[rl*2 + 1];
                    const float sc = rsqrtf(tot * (1.0f/128.0f) + 1.1920928955078125e-07f) * osc;
                    const int b = row >> 11, t = row & (T_ - 1);
                    ushort* orow = outp + ((size_t)(b * nh + hh) * T_ + t) * D_;
                    #pragma unroll
                    for (int nf = 0; nf < 2; nf++) {
                        const int ipair = WN * 32 + nf*16 + m16;
                        const float c = cosb[t*64 + ipair], s = sinb[t*64 + ipair];
                        const float x1 = acc[mf][nf][reg], x2 = acc[mf][nf+2][reg];
                        const int oc = WN * 64 + nf*16 + m16;
                        orow[oc]      = f2bf((x1*c + x2*s) * sc);
                        orow[oc + 32] = f2bf((x2*c - x1*s) * sc);
                    }
                }
            }
        }
    } else {
        // plain fp32 C
        #pragma unroll
        for (int mf = 0; mf < 4; mf++) {
            const int rl = WM*64 + mf*16 + quad*4;
            #pragma unroll
            for (int reg = 0; reg < 4; reg++) {
                float* cr = Cf + (size_t)(bm + rl + reg) * C_ + bn + WN*64 + m16;
                #pragma unroll
                for (int nf = 0; nf < 4; nf++)
                    cr[nf*16] = acc[mf][nf][reg];
            }
        }
    }
}

// ---------------------------------------------------------------------------
// Fused segmented fp32->bf16 cast of x, Wq, Wk, Wv, Wproj (one launch).
// ---------------------------------------------------------------------------
#define SEG0 1572864   // x      : 4096*1536/4
#define SEG1 2162688   // + Wq   : 1536*1536/4
#define SEG2 2359296   // + Wk   : 512*1536/4
#define SEG3 2555904   // + Wv   : 512*1536/4
#define SEG4 3145728   // + Wproj: 1536*1536/4
#define ROW4 384       // float4s per 1536-col row
__global__ __launch_bounds__(256) void cast_all(const float* __restrict__ x,
                                                const float* __restrict__ Wq,
                                                const float* __restrict__ Wk,
                                                const float* __restrict__ Wv,
                                                const float* __restrict__ Wp,
                                                ushort* __restrict__ xb,
                                                ushort* __restrict__ Wqkvb,
                                                ushort* __restrict__ Wpb) {
    const int i = blockIdx.x * 256 + threadIdx.x;
    float4 v; size_t dst4; ushort* dstp;
    if (i < SEG0) {
        v = ((const float4*)x)[i]; dstp = xb; dst4 = i;
    } else if (i < SEG1) {
        const int j = i - SEG0;
        const int r = j / ROW4, c4 = j - r * ROW4;
        const int d = r & 127, hh = r >> 7;
        v = ((const float4*)Wq)[j]; dstp = Wqkvb;
        dst4 = (size_t)(hh * 128 + dperm(d)) * ROW4 + c4;
    } else if (i < SEG2) {
        const int j = i - SEG1;
        const int r = j / ROW4, c4 = j - r * ROW4;
        const int d = r & 127, g = r >> 7;
        v = ((const float4*)Wk)[j]; dstp = Wqkvb;
        dst4 = (size_t)(1536 + g * 128 + dperm(d)) * ROW4 + c4;
    } else if (i < SEG3) {
        const int j = i - SEG2;
        v = ((const float4*)Wv)[j]; dstp = Wqkvb;
        dst4 = (size_t)2048 * ROW4 + j;
    } else {
        const int j = i - SEG3;
        v = ((const float4*)Wp)[j]; dstp = Wpb; dst4 = j;
    }
    ((ushort4*)dstp)[dst4] = make_ushort4(f2bf(v.x), f2bf(v.y), f2bf(v.z), f2bf(v.w));
}

// ---------------------------------------------------------------------------
// Flash attention: block = (b, h, 64 queries), 4 waves x 16 queries.
// r7 double-buffered body (counted vmcnt, never 0 mid-loop). Unchanged.
// ---------------------------------------------------------------------------
__global__ __launch_bounds__(256, 3) void attn_mfma(const ushort* __restrict__ Qp,
                                                    const ushort* __restrict__ Kp,
                                                    const ushort* __restrict__ Vt,
                                                    ushort* __restrict__ Y,
                                                    const int* __restrict__ wptr) {
    const int t0 = blockIdx.x * 64;
    const int h  = blockIdx.y, b = blockIdx.z;
    const int g  = h / REP_;
    const int tid  = threadIdx.x;
    const int wave = tid >> 6, lane = tid & 63;
    const int m16 = lane & 15, quad = lane >> 4;

    __shared__ ushort Ks[2][4096];       // [buf][4 kc x 2 halves x 16 x 32]
    __shared__ ushort Vs[2][4096];       // [buf][128 d x 32 keys]
    __shared__ ushort Pl[4][16 * 40];    // per-wave P buffers

    const int w = *wptr;
    const bool windowed = (w >= 0 && w < T_);
    const unsigned wu = windowed ? (unsigned)w : 0x7FFFFFFFu;
    int s_lo = 0;
    if (windowed) { s_lo = t0 - w; if (s_lo < 0) s_lo = 0; }
    const int s_hi = t0 + 63;
    const int ss0 = s_lo & ~31;
    const int NST = ((s_hi - ss0) >> 5) + 1;   // >= 2 always
    const int tw = t0 + wave * 16;

    const ushort* qrow = Qp + ((size_t)(b * H_ + h) * T_ + tw + m16) * D_ + quad * 8;
    bf16x8 qa[4];
    #pragma unroll
    for (int kc = 0; kc < 4; kc++) qa[kc] = ldb8(qrow + kc * 32);

    const ushort* kbase = Kp + (size_t)(b * KV_ + g) * T_ * D_;
    const ushort* vbase = Vt + (size_t)(b * KV_ + g) * D_ * T_;

    const int c0 = wave, c1 = wave + 4;
    const ushort* kg0 = kbase + (size_t)((c0 & 1) * 16 + (lane >> 2)) * D_ + (c0 >> 1) * 32 + (lane & 3) * 8;
    const ushort* kg1 = kbase + (size_t)((c1 & 1) * 16 + (lane >> 2)) * D_ + (c1 >> 1) * 32 + (lane & 3) * 8;
    const ushort* vg0 = vbase + (size_t)(c0 * 16 + (lane >> 2)) * T_ + (lane & 3) * 8;
    const ushort* vg1 = vbase + (size_t)(c1 * 16 + (lane >> 2)) * T_ + (lane & 3) * 8;
    const int kl0o = c0 * 512, kl1o = c1 * 512;

    auto stg = [&](int st, int buf) {
        const int ss = ss0 + (st << 5);
        const size_t koff = (size_t)ss * D_;
        async_copy16(kg0 + koff, Ks[buf] + kl0o);
        async_copy16(kg1 + koff, Ks[buf] + kl1o);
        async_copy16(vg0 + ss,   Vs[buf] + kl0o);
        async_copy16(vg1 + ss,   Vs[buf] + kl1o);
    };

    f32x4 o[8];
    #pragma unroll
    for (int dt = 0; dt < 8; dt++) o[dt] = (f32x4){0.f, 0.f, 0.f, 0.f};
    f32x4 lacc = (f32x4){0.f, 0.f, 0.f, 0.f};
    BCast onesc; onesc.u = (u32x4){0x3F803F80u, 0x3F803F80u, 0x3F803F80u, 0x3F803F80u};
    const bf16x8 ones = onesc.b;
    ushort* pw = &Pl[wave][0];

    stg(0, 0); stg(1, 1);
    __builtin_amdgcn_s_waitcnt(0x0F74);   // vmcnt(4)
    __builtin_amdgcn_sched_barrier(0);
    __builtin_amdgcn_s_barrier();
    __builtin_amdgcn_sched_barrier(0);

    #pragma unroll 1
    for (int st = 0; st < NST; st++) {
        const int ss = ss0 + (st << 5);
        const ushort* KsB = Ks[st & 1];
        const ushort* VsB = Vs[st & 1];

        f32x4 s0 = (f32x4){0.f,0.f,0.f,0.f};
        f32x4 s1 = (f32x4){0.f,0.f,0.f,0.f};
        #pragma unroll
        for (int kc = 0; kc < 4; kc++) {
            bf16x8 kf0 = ldb8(KsB + kc * 1024 + m16 * 32 + quad * 8);
            bf16x8 kf1 = ldb8(KsB + kc * 1024 + (16 + m16) * 32 + quad * 8);
            s0 = __builtin_amdgcn_mfma_f32_16x16x32_bf16(qa[kc], kf0, s0, 0, 0, 0);
            s1 = __builtin_amdgcn_mfma_f32_16x16x32_bf16(qa[kc], kf1, s1, 0, 0, 0);
        }

        const int sA = ss + m16, sB = ss + 16 + m16;
        #pragma unroll
        for (int reg = 0; reg < 4; reg++) {
            const int t = tw + quad * 4 + reg;
            const float pa = ((unsigned)(t - sA) <= wu) ? __expf(s0[reg]) : 0.f;
            const float pb = ((unsigned)(t - sB) <= wu) ? __expf(s1[reg]) : 0.f;
            pw[(quad * 4 + reg) * 40 + m16]      = f2bf(pa);
            pw[(quad * 4 + reg) * 40 + 16 + m16] = f2bf(pb);
        }

        __builtin_amdgcn_s_waitcnt(0xc07f);   // lgkmcnt(0), leave vmcnt alone
        bf16x8 pfrag = ldb8(pw + m16 * 40 + quad * 8);

        #pragma unroll
        for (int dt = 0; dt < 8; dt++) {
            bf16x8 vf = ldb8(VsB + (dt * 16 + m16) * 32 + quad * 8);
            o[dt] = __builtin_amdgcn_mfma_f32_16x16x32_bf16(pfrag, vf, o[dt], 0, 0, 0);
        }
        lacc = __builtin_amdgcn_mfma_f32_16x16x32_bf16(pfrag, ones, lacc, 0, 0, 0);

        if (st < NST - 1) {
            __builtin_amdgcn_sched_barrier(0);
            __builtin_amdgcn_s_barrier();      // Bar1: cur buf read-complete
            __builtin_amdgcn_sched_barrier(0);
            if (st < NST - 2) {
                stg(st + 2, st & 1);
                __builtin_amdgcn_s_waitcnt(0x0F74);  // vmcnt(4): st+1 landed
            } else {
                __builtin_amdgcn_s_waitcnt(0x0F70);  // vmcnt(0): drain tail
            }
            __builtin_amdgcn_sched_barrier(0);
            __builtin_amdgcn_s_barrier();      // Bar2: nxt buf certified
            __builtin_amdgcn_sched_barrier(0);
        }
    }

    float inv[4];
    #pragma unroll
    for (int reg = 0; reg < 4; reg++) inv[reg] = 1.0f / lacc[reg];
    ushort* yb = Y + ((size_t)(b * T_ + tw + quad * 4) * H_ + h) * D_ + m16;
    #pragma unroll
    for (int reg = 0; reg < 4; reg++)
        #pragma unroll
        for (int dt = 0; dt < 8; dt++)
            yb[(size_t)reg * H_ * D_ + dt * 16] = f2bf(o[dt][reg] * inv[reg]);
}

// ---------------------------------------------------------------------------
extern "C" void kernel_launch(void* const* d_in, const int* in_sizes, int n_in,
                              void* d_out, int out_size, void* d_ws, size_t ws_size,
                              hipStream_t stream) {
    const float* x     = (const float*)d_in[0];
    const float* ve    = (const float*)d_in[1];
    const float* cosb  = (const float*)d_in[2];
    const float* sinb  = (const float*)d_in[3];
    const float* Wq    = (const float*)d_in[4];
    const float* Wk    = (const float*)d_in[5];
    const float* Wv    = (const float*)d_in[6];
    const float* Wproj = (const float*)d_in[7];
    const float* Wg    = (const float*)d_in[8];
    const int*   wptr  = (const int*)d_in[9];
    float* out = (float*)d_out;

    // workspace layout (all bf16/ushort), ~63 MB (vbuf slot retired, layout
    // kept identical to minimize diff risk)
    ushort* xb    = (ushort*)d_ws;                    // M*C
    ushort* vbuf  = xb    + (size_t)M_ * C_;          // (unused)
    ushort* Qp    = vbuf  + (size_t)M_ * 512;         // M*C (permuted d)
    ushort* Kp    = Qp    + (size_t)M_ * C_;          // M*512 (permuted d)
    ushort* Vt    = Kp    + (size_t)M_ * 512;         // M*512
    ushort* yb16  = Vt    + (size_t)M_ * 512;         // M*C
    ushort* Wqkvb = yb16  + (size_t)M_ * C_;          // 2560*C (q/k rows dperm'd)
    ushort* Wpb   = Wqkvb + (size_t)NQKV_ * C_;       // C*C

    cast_all<<<SEG4 / 256, 256, 0, stream>>>(x, Wq, Wk, Wv, Wproj, xb, Wqkvb, Wpb);

    // qkv projection; v-tiles apply ve-gate and write Vt directly
    gemm128<0><<<dim3(NQKV_ / 128, M_ / 128), 256, 0, stream>>>(
        xb, Wqkvb, Qp, Kp, Vt, nullptr, cosb, sinb, x, ve, Wg);

    attn_mfma<<<dim3(T_ / 64, H_, B_), 256, 0, stream>>>(Qp, Kp, Vt, yb16, wptr);

    gemm128<1><<<dim3(C_ / 128, M_ / 128), 256, 0, stream>>>(
        yb16, Wpb, nullptr, nullptr, nullptr, out, nullptr, nullptr,
        nullptr, nullptr, nullptr);
}